// Round 4
// baseline (719.574 us; speedup 1.0000x reference)
//
#include <hip/hip_runtime.h>
#include <hip/hip_bf16.h>
#include <math.h>

#define S_LEN   2048
#define H_DIM   1024
#define N_QH    16
#define N_KVH   8
#define HEADD   64
#define FF_DIM  2048
#define N_EXP   4
#define WIN     512
#define QB      16

typedef __attribute__((ext_vector_type(8))) short bf16x8;
typedef __attribute__((ext_vector_type(4))) float f32x4;

__device__ __forceinline__ short f2bf(float x) {
  unsigned u = __float_as_uint(x);
  u += 0x7fffu + ((u >> 16) & 1u);
  return (short)(u >> 16);
}
__device__ __forceinline__ float bf2f(short h) {
  return __uint_as_float((unsigned)(unsigned short)h << 16);
}
// T2 XOR swizzle for [128][64]-short LDS tiles: bank-conflict-free ds_read_b128
// on the "16 lanes read 16 rows at same col" MFMA fragment pattern.
__device__ __forceinline__ int swz(int row, int col) {   // col in shorts, [0,64)
  return row * 64 + (col ^ ((row & 7) << 3));
}

// ---------------- rope tables in fp64 (match np/fp64 reference closely) ----------------
__global__ __launch_bounds__(256) void k_rope_tables(float* __restrict__ ct, float* __restrict__ st) {
  int i = blockIdx.x * 256 + threadIdx.x;   // t*32+d, 2048*32 total
  int t = i >> 5, d = i & 31;
  double inv = 1.0 / pow(10000.0, (double)d / 32.0);
  double ang = (double)t * inv;
  ct[i] = (float)cos(ang);
  st[i] = (float)sin(ang);
}

// ---------------- rmsnorm over H=1024 ----------------
// MODE 2: write split hi/lo bf16 (GEMM A operand)
// MODE 3: write single bf16 + fused gate top-2 routing -> wd
template <int MODE>
__global__ __launch_bounds__(256) void k_rmsnorm(const float* __restrict__ x,
                                                 const float* __restrict__ w,
                                                 short* __restrict__ yh,
                                                 short* __restrict__ yl,
                                                 const float* __restrict__ gw,
                                                 float* __restrict__ wd) {
  int row = blockIdx.x;
  const float4 v = ((const float4*)(x + (long)row * H_DIM))[threadIdx.x];
  float ss = v.x * v.x + v.y * v.y + v.z * v.z + v.w * v.w;
  for (int off = 32; off; off >>= 1) ss += __shfl_xor(ss, off);
  __shared__ float red[4];
  if ((threadIdx.x & 63) == 0) red[threadIdx.x >> 6] = ss;
  __syncthreads();
  ss = red[0] + red[1] + red[2] + red[3];
  float r = (float)(1.0 / sqrt((double)ss * (1.0 / 1024.0) + 1e-5));
  const float4 wv = ((const float4*)w)[threadIdx.x];
  float4 o;
  o.x = v.x * r * wv.x; o.y = v.y * r * wv.y; o.z = v.z * r * wv.z; o.w = v.w * r * wv.w;
  if (MODE == 2) {
    short h0 = f2bf(o.x), h1 = f2bf(o.y), h2 = f2bf(o.z), h3 = f2bf(o.w);
    short l0 = f2bf(o.x - bf2f(h0)), l1 = f2bf(o.y - bf2f(h1));
    short l2 = f2bf(o.z - bf2f(h2)), l3 = f2bf(o.w - bf2f(h3));
    uint2 hv = make_uint2((unsigned short)h0 | ((unsigned)(unsigned short)h1 << 16),
                          (unsigned short)h2 | ((unsigned)(unsigned short)h3 << 16));
    uint2 lv = make_uint2((unsigned short)l0 | ((unsigned)(unsigned short)l1 << 16),
                          (unsigned short)l2 | ((unsigned)(unsigned short)l3 << 16));
    ((uint2*)(yh + (long)row * H_DIM))[threadIdx.x] = hv;
    ((uint2*)(yl + (long)row * H_DIM))[threadIdx.x] = lv;
  }
  if (MODE == 3) {
    unsigned lo = (unsigned short)f2bf(o.x) | ((unsigned)(unsigned short)f2bf(o.y) << 16);
    unsigned hi = (unsigned short)f2bf(o.z) | ((unsigned)(unsigned short)f2bf(o.w) << 16);
    ((uint2*)(yh + (long)row * H_DIM))[threadIdx.x] = make_uint2(lo, hi);
    // fused gate: logits[e] = xn2 . gw[:,e]   (fp32, routing-critical)
    int i0 = threadIdx.x * 4;
    float4 g0 = *(const float4*)&gw[(i0 + 0) * 4];
    float4 g1 = *(const float4*)&gw[(i0 + 1) * 4];
    float4 g2 = *(const float4*)&gw[(i0 + 2) * 4];
    float4 g3 = *(const float4*)&gw[(i0 + 3) * 4];
    float p0 = o.x * g0.x + o.y * g1.x + o.z * g2.x + o.w * g3.x;
    float p1 = o.x * g0.y + o.y * g1.y + o.z * g2.y + o.w * g3.y;
    float p2 = o.x * g0.z + o.y * g1.z + o.z * g2.z + o.w * g3.z;
    float p3 = o.x * g0.w + o.y * g1.w + o.z * g2.w + o.w * g3.w;
    for (int off = 32; off; off >>= 1) {
      p0 += __shfl_xor(p0, off); p1 += __shfl_xor(p1, off);
      p2 += __shfl_xor(p2, off); p3 += __shfl_xor(p3, off);
    }
    __shared__ float gred[4][4];
    int wid = threadIdx.x >> 6;
    if ((threadIdx.x & 63) == 0) { gred[wid][0] = p0; gred[wid][1] = p1; gred[wid][2] = p2; gred[wid][3] = p3; }
    __syncthreads();
    if (threadIdx.x == 0) {
      float l[4];
      for (int e = 0; e < 4; ++e) l[e] = gred[0][e] + gred[1][e] + gred[2][e] + gred[3][e];
      int i1 = 0;
      for (int e = 1; e < 4; ++e) if (l[e] > l[i1]) i1 = e;          // lowest index on ties
      int i2 = -1;
      for (int e = 0; e < 4; ++e) { if (e == i1) continue; if (i2 < 0 || l[e] > l[i2]) i2 = e; }
      float e2 = expf(l[i2] - l[i1]);
      float w1 = 1.f / (1.f + e2);
      float ov[4] = {0.f, 0.f, 0.f, 0.f};
      ov[i1] = w1; ov[i2] = 1.f - w1;
      wd[row * 4 + 0] = ov[0]; wd[row * 4 + 1] = ov[1];
      wd[row * 4 + 2] = ov[2]; wd[row * 4 + 3] = ov[3];
    }
  }
}

// ---------------- transpose + split fp32(R,C) -> hi/lo bf16 (C,R) ----------------
__global__ __launch_bounds__(256) void k_tsplit(const float* __restrict__ in,
                                                short* __restrict__ oh,
                                                short* __restrict__ ol, int R, int C) {
  __shared__ float tile[32][33];
  int bx = blockIdx.x, by = blockIdx.y;
  int lx = threadIdx.x & 31, ly = threadIdx.x >> 5;
  int xc = bx * 32 + lx;
#pragma unroll
  for (int k = 0; k < 4; ++k) {
    int y = by * 32 + ly + k * 8;
    tile[ly + k * 8][lx] = in[(long)y * C + xc];
  }
  __syncthreads();
  int ox = by * 32 + lx;
#pragma unroll
  for (int k = 0; k < 4; ++k) {
    int oy = bx * 32 + ly + k * 8;
    float v = tile[lx][ly + k * 8];
    short hb = f2bf(v);
    short lb = f2bf(v - bf2f(hb));
    oh[(long)oy * R + ox] = hb;
    ol[(long)oy * R + ox] = lb;
  }
}

// ---------------- transpose + cast fp32(R,C) -> bf16(C,R) ----------------
__global__ __launch_bounds__(256) void k_transpose_cast(const float* __restrict__ in,
                                                        short* __restrict__ out,
                                                        int R, int C) {
  __shared__ float tile[32][33];
  int bx = blockIdx.x, by = blockIdx.y;
  int lx = threadIdx.x & 31, ly = threadIdx.x >> 5;
  int x = bx * 32 + lx;
#pragma unroll
  for (int k = 0; k < 4; ++k) {
    int y = by * 32 + ly + k * 8;
    tile[ly + k * 8][lx] = in[(long)y * C + x];
  }
  __syncthreads();
  int ox = by * 32 + lx;
#pragma unroll
  for (int k = 0; k < 4; ++k) {
    int oy = bx * 32 + ly + k * 8;
    out[(long)oy * R + ox] = f2bf(tile[lx][ly + k * 8]);
  }
}

// ---------------- split-bf16 "fp32" GEMM: C = Ahi.Bhi + Ahi.Blo + Alo.Bhi (+R) ----------------
// A (M,K) row-major split, Bt (N,K) row-major split (i.e. B^T), C fp32 (M,N)
template <int ADD>
__global__ __launch_bounds__(256) void k_gemm_split(const short* __restrict__ Ah,
                                                    const short* __restrict__ Al,
                                                    const short* __restrict__ Bh,
                                                    const short* __restrict__ Bl,
                                                    const float* __restrict__ R,
                                                    float* __restrict__ C,
                                                    int K, int ldA, int ldB, int ldC) {
  __shared__ short AsH[128 * 64], AsL[128 * 64], BsH[128 * 64], BsL[128 * 64];
  const int r0 = blockIdx.x * 128, c0 = blockIdx.y * 128;
  const int tid = threadIdx.x;
  const int wid = tid >> 6, lane = tid & 63;
  const int wr = wid >> 1, wc = wid & 1;
  const int lr = lane & 15, lg = lane >> 4;
  f32x4 zero = {0.f, 0.f, 0.f, 0.f};
  f32x4 acc[4][4];
#pragma unroll
  for (int m = 0; m < 4; ++m)
#pragma unroll
    for (int n = 0; n < 4; ++n) acc[m][n] = zero;
  for (int k0 = 0; k0 < K; k0 += 64) {
#pragma unroll
    for (int it = 0; it < 4; ++it) {
      int flat = tid + it * 256;
      int row = flat >> 3, cb = (flat & 7) * 8;
      int d = swz(row, cb);
      *(uint4*)&AsH[d] = *(const uint4*)&Ah[(long)(r0 + row) * ldA + k0 + cb];
      *(uint4*)&AsL[d] = *(const uint4*)&Al[(long)(r0 + row) * ldA + k0 + cb];
      *(uint4*)&BsH[d] = *(const uint4*)&Bh[(long)(c0 + row) * ldB + k0 + cb];
      *(uint4*)&BsL[d] = *(const uint4*)&Bl[(long)(c0 + row) * ldB + k0 + cb];
    }
    __syncthreads();
#pragma unroll
    for (int kk = 0; kk < 64; kk += 32) {
      bf16x8 ah[4], al[4], bh[4], bl[4];
#pragma unroll
      for (int m = 0; m < 4; ++m) {
        int d = swz(wr * 64 + m * 16 + lr, kk + lg * 8);
        ah[m] = *(const bf16x8*)&AsH[d];
        al[m] = *(const bf16x8*)&AsL[d];
      }
#pragma unroll
      for (int n = 0; n < 4; ++n) {
        int d = swz(wc * 64 + n * 16 + lr, kk + lg * 8);
        bh[n] = *(const bf16x8*)&BsH[d];
        bl[n] = *(const bf16x8*)&BsL[d];
      }
#pragma unroll
      for (int m = 0; m < 4; ++m)
#pragma unroll
        for (int n = 0; n < 4; ++n) {
          acc[m][n] = __builtin_amdgcn_mfma_f32_16x16x32_bf16(ah[m], bh[n], acc[m][n], 0, 0, 0);
          acc[m][n] = __builtin_amdgcn_mfma_f32_16x16x32_bf16(ah[m], bl[n], acc[m][n], 0, 0, 0);
          acc[m][n] = __builtin_amdgcn_mfma_f32_16x16x32_bf16(al[m], bh[n], acc[m][n], 0, 0, 0);
        }
    }
    __syncthreads();
  }
#pragma unroll
  for (int m = 0; m < 4; ++m)
#pragma unroll
    for (int n = 0; n < 4; ++n) {
      int col = c0 + wc * 64 + n * 16 + lr;
#pragma unroll
      for (int r = 0; r < 4; ++r) {
        int row = r0 + wr * 64 + m * 16 + lg * 4 + r;
        float v = acc[m][n][r];
        if (ADD) v += R[(long)row * ldC + col];
        C[(long)row * ldC + col] = v;
      }
    }
}

// ---------------- rope + per-head rms on q,k (in place on qkv buffer) ----------------
__global__ __launch_bounds__(256) void k_rope_rms(float* __restrict__ qkv,
                                                  const float* __restrict__ qn_w,
                                                  const float* __restrict__ kn_w,
                                                  const float* __restrict__ ct,
                                                  const float* __restrict__ st) {
  int idx = blockIdx.x * 4 + (threadIdx.x >> 6);  // head-slot 0 .. 2048*24-1
  int lane = threadIdx.x & 63;
  int t = idx / 24, hh = idx - t * 24;
  long base; const float* w;
  if (hh < N_QH) { base = (long)t * 2048 + hh * HEADD;              w = qn_w; }
  else           { base = (long)t * 2048 + 1024 + (hh - N_QH) * HEADD; w = kn_w; }
  float x = qkv[base + lane];
  float partner = __shfl_xor(x, 32);
  int d = lane & 31;
  float cs = ct[t * 32 + d], sn = st[t * 32 + d];
  float r = x * cs + partner * ((lane < 32) ? -sn : sn);
  float ss = r * r;
  for (int off = 32; off; off >>= 1) ss += __shfl_xor(ss, off);
  float rr = (float)(1.0 / sqrt((double)ss * (1.0 / 64.0) + 1e-5));
  qkv[base + lane] = r * rr * w[lane];
}

// ---------------- MFMA windowed attention, split-bf16 (~fp32 accurate) ----------------
// Per block: one head, QB=16 query rows, 4 waves.
// Phase 1 (per 64-key chunk): stage split K [64][72]; wave w computes S-tile
//   (16q x 16k, ksub=w) via 3-pass split MFMA; cap/mask -> sc f32.
// Phase 2: wave-parallel softmax (max, exp, sum) -> row_a = 1.06/sum.
// Phase 3: P -> clip -> packed split bf16 (hi|lo) in place in sc.
// Phase 4 (per chunk): stage split V^T into K-tile LDS; wave w computes
//   attn d-subtile (16q x 16d) via 3-pass split MFMA; split-bf16 global store.
__global__ __launch_bounds__(256) void k_attn_mfma(const float* __restrict__ qkv,
                                                   short* __restrict__ attHi,
                                                   short* __restrict__ attLo) {
  __shared__ short Kh[64][72], Kl[64][72];     // K tiles; reused as V^T [d][key] in PV
  __shared__ float sc[QB][580];                // scores f32; later packed P (hi|lo) u32
  __shared__ float row_a[QB];
  const int i0 = blockIdx.x * QB;
  const int hq = blockIdx.y;
  const int kvh = hq >> 1;
  const int tid = threadIdx.x;
  const int wv = tid >> 6, lane = tid & 63;
  const int lr = lane & 15, lg = lane >> 4;
  const int jstart = max(0, i0 - (WIN - 1));
  const int nch = (i0 + QB - jstart + 63) >> 6;   // <= 9
  const int ncols = nch * 64;
  f32x4 zero = {0.f, 0.f, 0.f, 0.f};

  // Q fragments in registers (A operand: row=q=lr, k = kk*32 + lg*8 + e), split hi/lo
  bf16x8 qh[2], ql[2];
  {
    const float* qp = &qkv[(long)(i0 + lr) * 2048 + hq * HEADD];
#pragma unroll
    for (int kk = 0; kk < 2; ++kk) {
      float4 f0 = *(const float4*)&qp[kk * 32 + lg * 8];
      float4 f1 = *(const float4*)&qp[kk * 32 + lg * 8 + 4];
      float ff[8] = {f0.x, f0.y, f0.z, f0.w, f1.x, f1.y, f1.z, f1.w};
      bf16x8 h, l;
#pragma unroll
      for (int u = 0; u < 8; ++u) {
        short hb = f2bf(ff[u]);
        h[u] = hb; l[u] = f2bf(ff[u] - bf2f(hb));
      }
      qh[kk] = h; ql[kk] = l;
    }
  }

  // ---- Phase 1: QK^T ----
  for (int ch = 0; ch < nch; ++ch) {
    int jb = jstart + ch * 64;
    {
      int key = tid >> 2, dbase = (tid & 3) * 16;
      int j = jb + key;
      const float* kp = &qkv[(long)j * 2048 + 1024 + kvh * HEADD];
#pragma unroll
      for (int q4 = 0; q4 < 4; ++q4) {
        int d = dbase + q4 * 4;
        float4 f = make_float4(0.f, 0.f, 0.f, 0.f);
        if (j < S_LEN) f = *(const float4*)&kp[d];
        short h0 = f2bf(f.x), h1 = f2bf(f.y), h2 = f2bf(f.z), h3 = f2bf(f.w);
        short l0 = f2bf(f.x - bf2f(h0)), l1 = f2bf(f.y - bf2f(h1));
        short l2 = f2bf(f.z - bf2f(h2)), l3 = f2bf(f.w - bf2f(h3));
        *(uint2*)&Kh[key][d] = make_uint2(
            (unsigned short)h0 | ((unsigned)(unsigned short)h1 << 16),
            (unsigned short)h2 | ((unsigned)(unsigned short)h3 << 16));
        *(uint2*)&Kl[key][d] = make_uint2(
            (unsigned short)l0 | ((unsigned)(unsigned short)l1 << 16),
            (unsigned short)l2 | ((unsigned)(unsigned short)l3 << 16));
      }
    }
    __syncthreads();
    f32x4 s = zero;
#pragma unroll
    for (int kk = 0; kk < 2; ++kk) {
      bf16x8 kh = *(const bf16x8*)&Kh[wv * 16 + lr][kk * 32 + lg * 8];
      bf16x8 kl = *(const bf16x8*)&Kl[wv * 16 + lr][kk * 32 + lg * 8];
      s = __builtin_amdgcn_mfma_f32_16x16x32_bf16(qh[kk], kh, s, 0, 0, 0);
      s = __builtin_amdgcn_mfma_f32_16x16x32_bf16(qh[kk], kl, s, 0, 0, 0);
      s = __builtin_amdgcn_mfma_f32_16x16x32_bf16(ql[kk], kh, s, 0, 0, 0);
    }
    int colbase = ch * 64 + wv * 16;
#pragma unroll
    for (int r = 0; r < 4; ++r) {
      int q = 4 * lg + r;
      int i = i0 + q;
      int j = jb + wv * 16 + lr;
      float v = s[r] * 0.125f;                 // 1/sqrt(64)
      v = 50.f * tanhf(v * 0.02f);             // softcap
      bool allow = (j <= i) && (i - j < WIN);
      sc[q][colbase + lr] = allow ? v : -1e30f;
    }
    __syncthreads();
  }

  // ---- Phase 2: softmax (rows wv*4 .. wv*4+3 per wave) ----
  for (int r = wv * 4; r < wv * 4 + 4; ++r) {
    float mx = -1e30f;
    for (int n = lane; n < ncols; n += 64) mx = fmaxf(mx, sc[r][n]);
    for (int off = 32; off; off >>= 1) mx = fmaxf(mx, __shfl_xor(mx, off));
    float sum = 0.f;
    for (int n = lane; n < ncols; n += 64) {
      float p = expf(sc[r][n] - mx);
      sc[r][n] = p; sum += p;
    }
    for (int off = 32; off; off >>= 1) sum += __shfl_xor(sum, off);
    if (lane == 0) row_a[r] = 1.06f / sum;
  }
  __syncthreads();

  // ---- Phase 3: P = clip(a*e - 0.03) -> packed split bf16 in place ----
  {
    int q = tid >> 4;
    float a = row_a[q];
    for (int n = (tid & 15); n < ncols; n += 16) {
      float e = sc[q][n];
      float p = fminf(fmaxf(fmaf(a, e, -0.03f), 0.f), 1.f);
      short ph = f2bf(p);
      short pl = f2bf(p - bf2f(ph));
      *(unsigned*)&sc[q][n] =
          (unsigned)(unsigned short)ph | ((unsigned)(unsigned short)pl << 16);
    }
  }
  __syncthreads();

  // ---- Phase 4: PV (wave wv owns d-subtile wv) ----
  f32x4 oacc = zero;
  for (int ch = 0; ch < nch; ++ch) {
    int jb = jstart + ch * 64;
    {
      int j = jb + (lane);                       // per wave: 64 keys
      int dbase = wv * 16;
      bool ok = (j < S_LEN);
      const float* vp = &qkv[(long)j * 2048 + 1536 + kvh * HEADD];
#pragma unroll
      for (int dd = 0; dd < 16; ++dd) {
        float f = ok ? vp[dbase + dd] : 0.f;
        short hb = f2bf(f);
        Kh[dbase + dd][lane] = hb;
        Kl[dbase + dd][lane] = f2bf(f - bf2f(hb));
      }
    }
    __syncthreads();
#pragma unroll
    for (int kk = 0; kk < 2; ++kk) {
      const unsigned* pp = (const unsigned*)&sc[lr][ch * 64 + kk * 32 + lg * 8];
      uint4 w0 = *(const uint4*)&pp[0];
      uint4 w1 = *(const uint4*)&pp[4];
      bf16x8 pa, pb;
      pa[0] = (short)w0.x; pb[0] = (short)(w0.x >> 16);
      pa[1] = (short)w0.y; pb[1] = (short)(w0.y >> 16);
      pa[2] = (short)w0.z; pb[2] = (short)(w0.z >> 16);
      pa[3] = (short)w0.w; pb[3] = (short)(w0.w >> 16);
      pa[4] = (short)w1.x; pb[4] = (short)(w1.x >> 16);
      pa[5] = (short)w1.y; pb[5] = (short)(w1.y >> 16);
      pa[6] = (short)w1.z; pb[6] = (short)(w1.z >> 16);
      pa[7] = (short)w1.w; pb[7] = (short)(w1.w >> 16);
      bf16x8 vh = *(const bf16x8*)&Kh[wv * 16 + lr][kk * 32 + lg * 8];
      bf16x8 vl = *(const bf16x8*)&Kl[wv * 16 + lr][kk * 32 + lg * 8];
      oacc = __builtin_amdgcn_mfma_f32_16x16x32_bf16(pa, vh, oacc, 0, 0, 0);
      oacc = __builtin_amdgcn_mfma_f32_16x16x32_bf16(pa, vl, oacc, 0, 0, 0);
      oacc = __builtin_amdgcn_mfma_f32_16x16x32_bf16(pb, vh, oacc, 0, 0, 0);
    }
    __syncthreads();
  }
  // C layout: col = d-within-subtile = lr, row = q = 4*lg + r
#pragma unroll
  for (int r = 0; r < 4; ++r) {
    int q = 4 * lg + r;
    int d = wv * 16 + lr;
    long ob = (long)(i0 + q) * 1024 + hq * HEADD + d;
    float v = oacc[r];
    short hb = f2bf(v);
    attHi[ob] = hb;
    attLo[ob] = f2bf(v - bf2f(hb));
  }
}

// ---------------- bf16 MFMA GEMM: C[M,N](f32) (+)= A[M,K] @ Bt[N,K]^T ----------------
template <int ATOMIC>
__global__ __launch_bounds__(256) void k_gemm_bf16(const short* __restrict__ A,
                                                   const short* __restrict__ Bt,
                                                   float* __restrict__ C,
                                                   int K, int ldA, int ldB, int ldC,
                                                   long sA, long sB, long sC) {
  __shared__ short As[128 * 64];
  __shared__ short Bs[128 * 64];
  const int e = blockIdx.z;
  A += (long)e * sA; Bt += (long)e * sB; C += (long)e * sC;
  const int r0 = blockIdx.x * 128, c0 = blockIdx.y * 128;
  const int tid = threadIdx.x;
  const int wid = tid >> 6, lane = tid & 63;
  const int wr = wid >> 1, wc = wid & 1;
  const int lr = lane & 15, lg = lane >> 4;
  f32x4 zero = {0.f, 0.f, 0.f, 0.f};
  f32x4 acc[4][4];
#pragma unroll
  for (int m = 0; m < 4; ++m)
#pragma unroll
    for (int n = 0; n < 4; ++n) acc[m][n] = zero;
  for (int k0 = 0; k0 < K; k0 += 64) {
#pragma unroll
    for (int it = 0; it < 4; ++it) {
      int flat = tid + it * 256;
      int row = flat >> 3, cb = (flat & 7) * 8;
      int d = swz(row, cb);
      *(uint4*)&As[d] = *(const uint4*)&A[(long)(r0 + row) * ldA + k0 + cb];
      *(uint4*)&Bs[d] = *(const uint4*)&Bt[(long)(c0 + row) * ldB + k0 + cb];
    }
    __syncthreads();
#pragma unroll
    for (int kk = 0; kk < 64; kk += 32) {
      bf16x8 af[4], bfr[4];
#pragma unroll
      for (int m = 0; m < 4; ++m) af[m] = *(const bf16x8*)&As[swz(wr * 64 + m * 16 + lr, kk + lg * 8)];
#pragma unroll
      for (int n = 0; n < 4; ++n) bfr[n] = *(const bf16x8*)&Bs[swz(wc * 64 + n * 16 + lr, kk + lg * 8)];
#pragma unroll
      for (int m = 0; m < 4; ++m)
#pragma unroll
        for (int n = 0; n < 4; ++n)
          acc[m][n] = __builtin_amdgcn_mfma_f32_16x16x32_bf16(af[m], bfr[n], acc[m][n], 0, 0, 0);
    }
    __syncthreads();
  }
#pragma unroll
  for (int m = 0; m < 4; ++m)
#pragma unroll
    for (int n = 0; n < 4; ++n) {
      int col = c0 + wc * 64 + n * 16 + lr;
#pragma unroll
      for (int r = 0; r < 4; ++r) {
        int row = r0 + wr * 64 + m * 16 + lg * 4 + r;
        float v = acc[m][n][r];
        if (ATOMIC) atomicAdd(&C[(long)row * ldC + col], v);
        else        C[(long)row * ldC + col] = v;
      }
    }
}

// ---------------- moe activation: a[e,t,f] = bf16( silu(g)*u * w_te ) ----------------
__global__ __launch_bounds__(256) void k_moe_act(const float* __restrict__ gu,
                                                 const float* __restrict__ wd,
                                                 short* __restrict__ aAll,
                                                 int e) {
  long i4 = (long)blockIdx.x * 256 + threadIdx.x;   // 2048*2048/4 = 1M float4
  int t  = (int)(i4 >> 9);
  int f4 = (int)(i4 & 511);
  float wte = wd[t * 4 + e];
  float4 g = ((const float4*)gu)[(long)t * 1024 + f4];
  float4 u = ((const float4*)gu)[(long)t * 1024 + 512 + f4];
  float4 s;
  s.x = wte * u.x * g.x / (1.f + expf(-g.x));
  s.y = wte * u.y * g.y / (1.f + expf(-g.y));
  s.z = wte * u.z * g.z / (1.f + expf(-g.z));
  s.w = wte * u.w * g.w / (1.f + expf(-g.w));
  unsigned lo = (unsigned short)f2bf(s.x) | ((unsigned)(unsigned short)f2bf(s.y) << 16);
  unsigned hi = (unsigned short)f2bf(s.z) | ((unsigned)(unsigned short)f2bf(s.w) << 16);
  ((uint2*)(aAll + ((long)e << 22)))[i4] = make_uint2(lo, hi);
}

extern "C" void kernel_launch(void* const* d_in, const int* in_sizes, int n_in,
                              void* d_out, int out_size, void* d_ws, size_t ws_size,
                              hipStream_t stream) {
  const float* x       = (const float*)d_in[0];
  const float* norm1_w = (const float*)d_in[1];
  const float* wq      = (const float*)d_in[2];
  const float* wk      = (const float*)d_in[3];
  const float* wv      = (const float*)d_in[4];
  const float* wo      = (const float*)d_in[5];
  const float* qn_w    = (const float*)d_in[6];
  const float* kn_w    = (const float*)d_in[7];
  const float* norm2_w = (const float*)d_in[8];
  const float* gate_w  = (const float*)d_in[9];
  const float* w_gate  = (const float*)d_in[10];
  const float* w_up    = (const float*)d_in[11];
  const float* w_down  = (const float*)d_in[12];
  float* out = (float*)d_out;
  char* ws = (char*)d_ws;
  const unsigned long MB = 1ul << 20;

  // workspace map (106 MB total; gu aliases [1,33); guT aliases dead h)
  float* ropeC = (float*)(ws + 0);               // 256 KB
  float* ropeS = (float*)(ws + 256 * 1024);      // 256 KB
  float* qkv   = (float*)(ws + 1 * MB);          // 16 MB  [1,17)
  short* xnHi  = (short*)(ws + 17 * MB);         // 4 MB
  short* xnLo  = (short*)(ws + 21 * MB);         // 4 MB
  short* attHi = (short*)(ws + 25 * MB);         // 4 MB
  short* attLo = (short*)(ws + 29 * MB);         // 4 MB
  float* gu    = (float*)(ws + 1 * MB);          // 32 MB, aliases qkv/xnS/attS (dead by MoE)
  short* qkvWh = (short*)(ws + 33 * MB);         // 4 MB
  short* qkvWl = (short*)(ws + 37 * MB);         // 4 MB
  short* woTh  = (short*)(ws + 41 * MB);         // 2 MB
  short* woTl  = (short*)(ws + 43 * MB);         // 2 MB
  float* h     = (float*)(ws + 45 * MB);         // 8 MB
  short* guT   = (short*)(ws + 45 * MB);         // 8 MB, aliases h (dead after memcpy)
  short* x2b   = (short*)(ws + 53 * MB);         // 4 MB
  float* wd    = (float*)(ws + 57 * MB);         // 32 KB
  short* dT    = (short*)(ws + 58 * MB);         // 16 MB
  short* aAll  = (short*)(ws + 74 * MB);         // 32 MB -> ends 106 MB

  k_rope_tables<<<256, 256, 0, stream>>>(ropeC, ropeS);
  k_rmsnorm<2><<<S_LEN, 256, 0, stream>>>(x, norm1_w, xnHi, xnLo, nullptr, nullptr);
  // transpose+split QKV weights into one Bt (2048 rows x 1024): q|k|v at rows 0|1024|1536
  k_tsplit<<<dim3(32, 32), 256, 0, stream>>>(wq, qkvWh, qkvWl, 1024, 1024);
  k_tsplit<<<dim3(16, 32), 256, 0, stream>>>(wk, qkvWh + 1024 * 1024, qkvWl + 1024 * 1024, 1024, 512);
  k_tsplit<<<dim3(16, 32), 256, 0, stream>>>(wv, qkvWh + 1536 * 1024, qkvWl + 1536 * 1024, 1024, 512);
  k_tsplit<<<dim3(32, 32), 256, 0, stream>>>(wo, woTh, woTl, 1024, 1024);
  // fused QKV projection (split-bf16 ~= fp32): qkv[t][0:1024|1024:1536|1536:2048]
  k_gemm_split<0><<<dim3(16, 16), 256, 0, stream>>>(xnHi, xnLo, qkvWh, qkvWl, nullptr, qkv,
                                                    1024, 1024, 1024, 2048);
  k_rope_rms<<<(S_LEN * 24) / 4, 256, 0, stream>>>(qkv, qn_w, kn_w, ropeC, ropeS);
  k_attn_mfma<<<dim3(S_LEN / QB, N_QH), 256, 0, stream>>>(qkv, attHi, attLo);
  // h = x + att @ wo   (split-bf16 ~= fp32)
  k_gemm_split<1><<<dim3(16, 8), 256, 0, stream>>>(attHi, attLo, woTh, woTl, x, h,
                                                   1024, 1024, 1024, 1024);
  k_rmsnorm<3><<<S_LEN, 256, 0, stream>>>(h, norm2_w, x2b, nullptr, gate_w, wd);
  hipMemcpyAsync(out, h, (size_t)S_LEN * H_DIM * sizeof(float), hipMemcpyDeviceToDevice, stream);
  // bf16 down-proj weights (all experts, needed by batched GEMM2)
  for (int e = 0; e < N_EXP; ++e)
    k_transpose_cast<<<dim3(1024 / 32, 2048 / 32), 256, 0, stream>>>(
        w_down + (long)e * FF_DIM * H_DIM, dT + (long)e * H_DIM * FF_DIM, 2048, 1024);
  // per-expert: transpose gate/up -> guT (aliases dead h), GEMM1 (N=4096), act -> aAll[e]
  for (int e = 0; e < N_EXP; ++e) {
    k_transpose_cast<<<dim3(2048 / 32, 1024 / 32), 256, 0, stream>>>(
        w_gate + (long)e * H_DIM * FF_DIM, guT, 1024, 2048);
    k_transpose_cast<<<dim3(2048 / 32, 1024 / 32), 256, 0, stream>>>(
        w_up + (long)e * H_DIM * FF_DIM, guT + (long)FF_DIM * H_DIM, 1024, 2048);
    k_gemm_bf16<0><<<dim3(16, 32), 256, 0, stream>>>(x2b, guT, gu, 1024, 1024, 1024, 4096, 0, 0, 0);
    k_moe_act<<<4096, 256, 0, stream>>>(gu, wd, aAll, e);
  }
  // batched GEMM2 over experts: out += a[e] @ w_down[e]  (atomicAdd epilogue)
  k_gemm_bf16<1><<<dim3(16, 8, N_EXP), 256, 0, stream>>>(
      aAll, dT, out, 2048, 2048, 2048, 1024,
      (long)S_LEN * FF_DIM, (long)H_DIM * FF_DIM, 0);
}

// Round 5
// 579.679 us; speedup vs baseline: 1.2413x; 1.2413x over previous
//
#include <hip/hip_runtime.h>
#include <hip/hip_bf16.h>
#include <math.h>

#define S_LEN   2048
#define H_DIM   1024
#define N_QH    16
#define N_KVH   8
#define HEADD   64
#define FF_DIM  2048
#define N_EXP   4
#define WIN     512
#define QB      16
#define SCS     596   // sc row stride (f32 words): mod 32 = 20 -> <=2-way banks

typedef __attribute__((ext_vector_type(8))) short bf16x8;
typedef __attribute__((ext_vector_type(4))) float f32x4;

__device__ __forceinline__ short f2bf(float x) {
  unsigned u = __float_as_uint(x);
  u += 0x7fffu + ((u >> 16) & 1u);
  return (short)(u >> 16);
}
__device__ __forceinline__ float bf2f(short h) {
  return __uint_as_float((unsigned)(unsigned short)h << 16);
}
__device__ __forceinline__ unsigned pk2(short a, short b) {
  return (unsigned)(unsigned short)a | ((unsigned)(unsigned short)b << 16);
}
// T2 XOR swizzle for [128][64]-short LDS tiles (GEMM): conflict-free ds_read_b128
__device__ __forceinline__ int swz(int row, int col) {   // col in shorts, [0,64)
  return row * 64 + (col ^ ((row & 7) << 3));
}

// ---------------- rope tables in fp64 (match np/fp64 reference closely) ----------------
__global__ __launch_bounds__(256) void k_rope_tables(float* __restrict__ ct, float* __restrict__ st) {
  int i = blockIdx.x * 256 + threadIdx.x;   // t*32+d, 2048*32 total
  int t = i >> 5, d = i & 31;
  double inv = 1.0 / pow(10000.0, (double)d / 32.0);
  double ang = (double)t * inv;
  ct[i] = (float)cos(ang);
  st[i] = (float)sin(ang);
}

// ---------------- rmsnorm over H=1024 ----------------
// MODE 2: write split hi/lo bf16 (GEMM A operand)
// MODE 3: write single bf16 + fused gate top-2 routing -> wd
template <int MODE>
__global__ __launch_bounds__(256) void k_rmsnorm(const float* __restrict__ x,
                                                 const float* __restrict__ w,
                                                 short* __restrict__ yh,
                                                 short* __restrict__ yl,
                                                 const float* __restrict__ gw,
                                                 float* __restrict__ wd) {
  int row = blockIdx.x;
  const float4 v = ((const float4*)(x + (long)row * H_DIM))[threadIdx.x];
  float ss = v.x * v.x + v.y * v.y + v.z * v.z + v.w * v.w;
  for (int off = 32; off; off >>= 1) ss += __shfl_xor(ss, off);
  __shared__ float red[4];
  if ((threadIdx.x & 63) == 0) red[threadIdx.x >> 6] = ss;
  __syncthreads();
  ss = red[0] + red[1] + red[2] + red[3];
  float r = (float)(1.0 / sqrt((double)ss * (1.0 / 1024.0) + 1e-5));
  const float4 wv = ((const float4*)w)[threadIdx.x];
  float4 o;
  o.x = v.x * r * wv.x; o.y = v.y * r * wv.y; o.z = v.z * r * wv.z; o.w = v.w * r * wv.w;
  if (MODE == 2) {
    short h0 = f2bf(o.x), h1 = f2bf(o.y), h2 = f2bf(o.z), h3 = f2bf(o.w);
    short l0 = f2bf(o.x - bf2f(h0)), l1 = f2bf(o.y - bf2f(h1));
    short l2 = f2bf(o.z - bf2f(h2)), l3 = f2bf(o.w - bf2f(h3));
    ((uint2*)(yh + (long)row * H_DIM))[threadIdx.x] = make_uint2(pk2(h0, h1), pk2(h2, h3));
    ((uint2*)(yl + (long)row * H_DIM))[threadIdx.x] = make_uint2(pk2(l0, l1), pk2(l2, l3));
  }
  if (MODE == 3) {
    ((uint2*)(yh + (long)row * H_DIM))[threadIdx.x] =
        make_uint2(pk2(f2bf(o.x), f2bf(o.y)), pk2(f2bf(o.z), f2bf(o.w)));
    // fused gate: logits[e] = xn2 . gw[:,e]   (fp32, routing-critical)
    int i0 = threadIdx.x * 4;
    float4 g0 = *(const float4*)&gw[(i0 + 0) * 4];
    float4 g1 = *(const float4*)&gw[(i0 + 1) * 4];
    float4 g2 = *(const float4*)&gw[(i0 + 2) * 4];
    float4 g3 = *(const float4*)&gw[(i0 + 3) * 4];
    float p0 = o.x * g0.x + o.y * g1.x + o.z * g2.x + o.w * g3.x;
    float p1 = o.x * g0.y + o.y * g1.y + o.z * g2.y + o.w * g3.y;
    float p2 = o.x * g0.z + o.y * g1.z + o.z * g2.z + o.w * g3.z;
    float p3 = o.x * g0.w + o.y * g1.w + o.z * g2.w + o.w * g3.w;
    for (int off = 32; off; off >>= 1) {
      p0 += __shfl_xor(p0, off); p1 += __shfl_xor(p1, off);
      p2 += __shfl_xor(p2, off); p3 += __shfl_xor(p3, off);
    }
    __shared__ float gred[4][4];
    int wid = threadIdx.x >> 6;
    if ((threadIdx.x & 63) == 0) { gred[wid][0] = p0; gred[wid][1] = p1; gred[wid][2] = p2; gred[wid][3] = p3; }
    __syncthreads();
    if (threadIdx.x == 0) {
      float l[4];
      for (int e = 0; e < 4; ++e) l[e] = gred[0][e] + gred[1][e] + gred[2][e] + gred[3][e];
      int i1 = 0;
      for (int e = 1; e < 4; ++e) if (l[e] > l[i1]) i1 = e;          // lowest index on ties
      int i2 = -1;
      for (int e = 0; e < 4; ++e) { if (e == i1) continue; if (i2 < 0 || l[e] > l[i2]) i2 = e; }
      float e2 = expf(l[i2] - l[i1]);
      float w1 = 1.f / (1.f + e2);
      float ov[4] = {0.f, 0.f, 0.f, 0.f};
      ov[i1] = w1; ov[i2] = 1.f - w1;
      wd[row * 4 + 0] = ov[0]; wd[row * 4 + 1] = ov[1];
      wd[row * 4 + 2] = ov[2]; wd[row * 4 + 3] = ov[3];
    }
  }
}

// ---------------- transpose + split fp32(R,C) -> hi/lo bf16 (C,R) ----------------
__global__ __launch_bounds__(256) void k_tsplit(const float* __restrict__ in,
                                                short* __restrict__ oh,
                                                short* __restrict__ ol, int R, int C) {
  __shared__ float tile[32][33];
  int bx = blockIdx.x, by = blockIdx.y;
  int lx = threadIdx.x & 31, ly = threadIdx.x >> 5;
  int xc = bx * 32 + lx;
#pragma unroll
  for (int k = 0; k < 4; ++k) {
    int y = by * 32 + ly + k * 8;
    tile[ly + k * 8][lx] = in[(long)y * C + xc];
  }
  __syncthreads();
  int ox = by * 32 + lx;
#pragma unroll
  for (int k = 0; k < 4; ++k) {
    int oy = bx * 32 + ly + k * 8;
    float v = tile[lx][ly + k * 8];
    short hb = f2bf(v);
    short lb = f2bf(v - bf2f(hb));
    oh[(long)oy * R + ox] = hb;
    ol[(long)oy * R + ox] = lb;
  }
}

// ---------------- transpose + cast fp32(R,C) -> bf16(C,R) ----------------
__global__ __launch_bounds__(256) void k_transpose_cast(const float* __restrict__ in,
                                                        short* __restrict__ out,
                                                        int R, int C) {
  __shared__ float tile[32][33];
  int bx = blockIdx.x, by = blockIdx.y;
  int lx = threadIdx.x & 31, ly = threadIdx.x >> 5;
  int x = bx * 32 + lx;
#pragma unroll
  for (int k = 0; k < 4; ++k) {
    int y = by * 32 + ly + k * 8;
    tile[ly + k * 8][lx] = in[(long)y * C + x];
  }
  __syncthreads();
  int ox = by * 32 + lx;
#pragma unroll
  for (int k = 0; k < 4; ++k) {
    int oy = bx * 32 + ly + k * 8;
    out[(long)oy * R + ox] = f2bf(tile[lx][ly + k * 8]);
  }
}

// ---------------- split-bf16 "fp32" GEMM: C = Ahi.Bhi + Ahi.Blo + Alo.Bhi (+R) ----------------
template <int ADD>
__global__ __launch_bounds__(256) void k_gemm_split(const short* __restrict__ Ah,
                                                    const short* __restrict__ Al,
                                                    const short* __restrict__ Bh,
                                                    const short* __restrict__ Bl,
                                                    const float* __restrict__ R,
                                                    float* __restrict__ C,
                                                    int K, int ldA, int ldB, int ldC) {
  __shared__ short AsH[128 * 64], AsL[128 * 64], BsH[128 * 64], BsL[128 * 64];
  const int r0 = blockIdx.x * 128, c0 = blockIdx.y * 128;
  const int tid = threadIdx.x;
  const int wid = tid >> 6, lane = tid & 63;
  const int wr = wid >> 1, wc = wid & 1;
  const int lr = lane & 15, lg = lane >> 4;
  f32x4 zero = {0.f, 0.f, 0.f, 0.f};
  f32x4 acc[4][4];
#pragma unroll
  for (int m = 0; m < 4; ++m)
#pragma unroll
    for (int n = 0; n < 4; ++n) acc[m][n] = zero;
  for (int k0 = 0; k0 < K; k0 += 64) {
#pragma unroll
    for (int it = 0; it < 4; ++it) {
      int flat = tid + it * 256;
      int row = flat >> 3, cb = (flat & 7) * 8;
      int d = swz(row, cb);
      *(uint4*)&AsH[d] = *(const uint4*)&Ah[(long)(r0 + row) * ldA + k0 + cb];
      *(uint4*)&AsL[d] = *(const uint4*)&Al[(long)(r0 + row) * ldA + k0 + cb];
      *(uint4*)&BsH[d] = *(const uint4*)&Bh[(long)(c0 + row) * ldB + k0 + cb];
      *(uint4*)&BsL[d] = *(const uint4*)&Bl[(long)(c0 + row) * ldB + k0 + cb];
    }
    __syncthreads();
#pragma unroll
    for (int kk = 0; kk < 64; kk += 32) {
      bf16x8 ah[4], al[4], bh[4], bl[4];
#pragma unroll
      for (int m = 0; m < 4; ++m) {
        int d = swz(wr * 64 + m * 16 + lr, kk + lg * 8);
        ah[m] = *(const bf16x8*)&AsH[d];
        al[m] = *(const bf16x8*)&AsL[d];
      }
#pragma unroll
      for (int n = 0; n < 4; ++n) {
        int d = swz(wc * 64 + n * 16 + lr, kk + lg * 8);
        bh[n] = *(const bf16x8*)&BsH[d];
        bl[n] = *(const bf16x8*)&BsL[d];
      }
#pragma unroll
      for (int m = 0; m < 4; ++m)
#pragma unroll
        for (int n = 0; n < 4; ++n) {
          acc[m][n] = __builtin_amdgcn_mfma_f32_16x16x32_bf16(ah[m], bh[n], acc[m][n], 0, 0, 0);
          acc[m][n] = __builtin_amdgcn_mfma_f32_16x16x32_bf16(ah[m], bl[n], acc[m][n], 0, 0, 0);
          acc[m][n] = __builtin_amdgcn_mfma_f32_16x16x32_bf16(al[m], bh[n], acc[m][n], 0, 0, 0);
        }
    }
    __syncthreads();
  }
#pragma unroll
  for (int m = 0; m < 4; ++m)
#pragma unroll
    for (int n = 0; n < 4; ++n) {
      int col = c0 + wc * 64 + n * 16 + lr;
#pragma unroll
      for (int r = 0; r < 4; ++r) {
        int row = r0 + wr * 64 + m * 16 + lg * 4 + r;
        float v = acc[m][n][r];
        if (ADD) v += R[(long)row * ldC + col];
        C[(long)row * ldC + col] = v;
      }
    }
}

// ---------------- rope + per-head rms on q,k (in place on qkv buffer) ----------------
__global__ __launch_bounds__(256) void k_rope_rms(float* __restrict__ qkv,
                                                  const float* __restrict__ qn_w,
                                                  const float* __restrict__ kn_w,
                                                  const float* __restrict__ ct,
                                                  const float* __restrict__ st) {
  int idx = blockIdx.x * 4 + (threadIdx.x >> 6);  // head-slot 0 .. 2048*24-1
  int lane = threadIdx.x & 63;
  int t = idx / 24, hh = idx - t * 24;
  long base; const float* w;
  if (hh < N_QH) { base = (long)t * 2048 + hh * HEADD;              w = qn_w; }
  else           { base = (long)t * 2048 + 1024 + (hh - N_QH) * HEADD; w = kn_w; }
  float x = qkv[base + lane];
  float partner = __shfl_xor(x, 32);
  int d = lane & 31;
  float cs = ct[t * 32 + d], sn = st[t * 32 + d];
  float r = x * cs + partner * ((lane < 32) ? -sn : sn);
  float ss = r * r;
  for (int off = 32; off; off >>= 1) ss += __shfl_xor(ss, off);
  float rr = (float)(1.0 / sqrt((double)ss * (1.0 / 64.0) + 1e-5));
  qkv[base + lane] = r * rr * w[lane];
}

// ---------------- K/V split pre-pass ----------------
// K -> Kb[kvh][j][d] hi/lo bf16 (row-major), V -> Vt[kvh][d][j] hi/lo bf16 (transposed).
// Conversion happens ONCE per element (attn previously re-converted each key ~32x).
__global__ __launch_bounds__(256) void k_kv_split(const float* __restrict__ qkv,
                                                  short* __restrict__ Kbh, short* __restrict__ Kbl,
                                                  short* __restrict__ Vth, short* __restrict__ Vtl) {
  const int kvh = blockIdx.y;
  const int jb = blockIdx.x * 64;
  const int tid = threadIdx.x;
  // K: thread owns row j, 16 contiguous d
  {
    int j = jb + (tid >> 2);
    int dq = (tid & 3) * 16;
    const float* kp = &qkv[(long)j * 2048 + 1024 + kvh * HEADD + dq];
    long ob = ((long)kvh * S_LEN + j) * HEADD + dq;
#pragma unroll
    for (int u4 = 0; u4 < 4; ++u4) {
      float4 f = *(const float4*)&kp[u4 * 4];
      short h0 = f2bf(f.x), h1 = f2bf(f.y), h2 = f2bf(f.z), h3 = f2bf(f.w);
      short l0 = f2bf(f.x - bf2f(h0)), l1 = f2bf(f.y - bf2f(h1));
      short l2 = f2bf(f.z - bf2f(h2)), l3 = f2bf(f.w - bf2f(h3));
      *(uint2*)&Kbh[ob + u4 * 4] = make_uint2(pk2(h0, h1), pk2(h2, h3));
      *(uint2*)&Kbl[ob + u4 * 4] = make_uint2(pk2(l0, l1), pk2(l2, l3));
    }
  }
  // V: thread owns col d, 16 contiguous j (transpose; reads coalesced across lanes)
  {
    int d = tid & 63;
    int j0 = jb + (tid >> 6) * 16;
    short hb[16], lb[16];
#pragma unroll
    for (int u = 0; u < 16; ++u) {
      float f = qkv[(long)(j0 + u) * 2048 + 1536 + kvh * HEADD + d];
      hb[u] = f2bf(f);
      lb[u] = f2bf(f - bf2f(hb[u]));
    }
    long ob = ((long)kvh * HEADD + d) * S_LEN + j0;
#pragma unroll
    for (int w = 0; w < 2; ++w) {
      uint4 oh, ol;
      oh.x = pk2(hb[w * 8 + 0], hb[w * 8 + 1]); oh.y = pk2(hb[w * 8 + 2], hb[w * 8 + 3]);
      oh.z = pk2(hb[w * 8 + 4], hb[w * 8 + 5]); oh.w = pk2(hb[w * 8 + 6], hb[w * 8 + 7]);
      ol.x = pk2(lb[w * 8 + 0], lb[w * 8 + 1]); ol.y = pk2(lb[w * 8 + 2], lb[w * 8 + 3]);
      ol.z = pk2(lb[w * 8 + 4], lb[w * 8 + 5]); ol.w = pk2(lb[w * 8 + 6], lb[w * 8 + 7]);
      *(uint4*)&Vth[ob + w * 8] = oh;
      *(uint4*)&Vtl[ob + w * 8] = ol;
    }
  }
}

// ---------------- MFMA windowed attention v2: K/V frags direct from global ----------------
// Block = (16-query tile, head), 4 waves. Only LDS: score matrix sc[16][SCS].
// jstart aligned to 64 so all global 16B frag loads are aligned; masked cols have P=0
// so clamped OOB V/K reads are harmless. 3 barriers per block total.
__global__ __launch_bounds__(256) void k_attn2(const float* __restrict__ qkv,
                                               const short* __restrict__ Kbh,
                                               const short* __restrict__ Kbl,
                                               const short* __restrict__ Vth,
                                               const short* __restrict__ Vtl,
                                               short* __restrict__ attHi,
                                               short* __restrict__ attLo) {
  __shared__ float sc[QB][SCS];
  __shared__ float row_a[QB];
  const int i0 = blockIdx.x * QB;
  const int hq = blockIdx.y;
  const int kvh = hq >> 1;
  const int tid = threadIdx.x;
  const int wv = tid >> 6, lane = tid & 63;
  const int lr = lane & 15, lg = lane >> 4;
  const int jstart = (i0 >= WIN) ? ((i0 - (WIN - 1)) & ~63) : 0;   // 64-aligned
  const int nch = (i0 + QB - jstart + 63) >> 6;                    // <= 9
  const int ncols = nch * 64;
  f32x4 zero = {0.f, 0.f, 0.f, 0.f};
  const short* Kh_p = Kbh + (long)kvh * S_LEN * HEADD;
  const short* Kl_p = Kbl + (long)kvh * S_LEN * HEADD;
  const short* Vh_p = Vth + (long)kvh * HEADD * S_LEN;
  const short* Vl_p = Vtl + (long)kvh * HEADD * S_LEN;

  // Q fragments in registers (A operand: row=q=lr, k = kk*32 + lg*8 + e), split hi/lo
  bf16x8 qh[2], ql[2];
  {
    const float* qp = &qkv[(long)(i0 + lr) * 2048 + hq * HEADD];
#pragma unroll
    for (int kk = 0; kk < 2; ++kk) {
      float4 f0 = *(const float4*)&qp[kk * 32 + lg * 8];
      float4 f1 = *(const float4*)&qp[kk * 32 + lg * 8 + 4];
      float ff[8] = {f0.x, f0.y, f0.z, f0.w, f1.x, f1.y, f1.z, f1.w};
      bf16x8 h, l;
#pragma unroll
      for (int u = 0; u < 8; ++u) {
        short hb = f2bf(ff[u]);
        h[u] = hb; l[u] = f2bf(ff[u] - bf2f(hb));
      }
      qh[kk] = h; ql[kk] = l;
    }
  }

  // ---- Phase 1: QK^T, no barriers (waves own disjoint sc columns) ----
  for (int ch = 0; ch < nch; ++ch) {
    int jb = jstart + ch * 64;
    int jrow = jb + wv * 16 + lr;          // this lane's key (B-frag row)
    int jc = min(jrow, S_LEN - 1);         // clamped rows are masked below
    f32x4 s = zero;
#pragma unroll
    for (int kk = 0; kk < 2; ++kk) {
      bf16x8 kh = *(const bf16x8*)&Kh_p[(long)jc * HEADD + kk * 32 + lg * 8];
      bf16x8 kl = *(const bf16x8*)&Kl_p[(long)jc * HEADD + kk * 32 + lg * 8];
      s = __builtin_amdgcn_mfma_f32_16x16x32_bf16(qh[kk], kh, s, 0, 0, 0);
      s = __builtin_amdgcn_mfma_f32_16x16x32_bf16(qh[kk], kl, s, 0, 0, 0);
      s = __builtin_amdgcn_mfma_f32_16x16x32_bf16(ql[kk], kh, s, 0, 0, 0);
    }
    int col = ch * 64 + wv * 16 + lr;
#pragma unroll
    for (int r = 0; r < 4; ++r) {
      int q = 4 * lg + r;
      int i = i0 + q;
      float v = s[r] * 0.125f;                 // 1/sqrt(64)
      v = 50.f * tanhf(v * 0.02f);             // softcap
      bool allow = (jrow <= i) && (i - jrow < WIN);
      sc[q][col] = allow ? v : -1e30f;
    }
  }
  __syncthreads();

  // ---- Phase 2: softmax (rows wv*4 .. wv*4+3 per wave) ----
  for (int r = wv * 4; r < wv * 4 + 4; ++r) {
    float mx = -1e30f;
    for (int n = lane; n < ncols; n += 64) mx = fmaxf(mx, sc[r][n]);
    for (int off = 32; off; off >>= 1) mx = fmaxf(mx, __shfl_xor(mx, off));
    float sum = 0.f;
    for (int n = lane; n < ncols; n += 64) {
      float p = expf(sc[r][n] - mx);
      sc[r][n] = p; sum += p;
    }
    for (int off = 32; off; off >>= 1) sum += __shfl_xor(sum, off);
    if (lane == 0) row_a[r] = 1.06f / sum;
  }
  __syncthreads();

  // ---- Phase 3: P = clip(a*e - 0.03) -> packed split bf16 (hi|lo) in place ----
  {
    int q = tid >> 4;
    float a = row_a[q];
    for (int n = (tid & 15); n < ncols; n += 16) {
      float e = sc[q][n];
      float p = fminf(fmaxf(fmaf(a, e, -0.03f), 0.f), 1.f);
      short ph = f2bf(p);
      short pl = f2bf(p - bf2f(ph));
      *(unsigned*)&sc[q][n] = pk2(ph, pl);
    }
  }
  __syncthreads();

  // ---- Phase 4: PV, V^T frags direct from global; no barriers ----
  f32x4 oacc = zero;
  for (int ch = 0; ch < nch; ++ch) {
    int jb = jstart + ch * 64;
#pragma unroll
    for (int kk = 0; kk < 2; ++kk) {
      int js = jb + kk * 32 + lg * 8;              // multiple of 8
      int jcb = min(js, S_LEN - 8);                // clamp only when ALL 8 keys OOB (P=0)
      const unsigned* pp = (const unsigned*)&sc[lr][ch * 64 + kk * 32 + lg * 8];
      uint4 w0 = *(const uint4*)&pp[0];
      uint4 w1 = *(const uint4*)&pp[4];
      bf16x8 pa, pb;
      pa[0] = (short)w0.x; pb[0] = (short)(w0.x >> 16);
      pa[1] = (short)w0.y; pb[1] = (short)(w0.y >> 16);
      pa[2] = (short)w0.z; pb[2] = (short)(w0.z >> 16);
      pa[3] = (short)w0.w; pb[3] = (short)(w0.w >> 16);
      pa[4] = (short)w1.x; pb[4] = (short)(w1.x >> 16);
      pa[5] = (short)w1.y; pb[5] = (short)(w1.y >> 16);
      pa[6] = (short)w1.z; pb[6] = (short)(w1.z >> 16);
      pa[7] = (short)w1.w; pb[7] = (short)(w1.w >> 16);
      bf16x8 vh = *(const bf16x8*)&Vh_p[(long)(wv * 16 + lr) * S_LEN + jcb];
      bf16x8 vl = *(const bf16x8*)&Vl_p[(long)(wv * 16 + lr) * S_LEN + jcb];
      oacc = __builtin_amdgcn_mfma_f32_16x16x32_bf16(pa, vh, oacc, 0, 0, 0);
      oacc = __builtin_amdgcn_mfma_f32_16x16x32_bf16(pa, vl, oacc, 0, 0, 0);
      oacc = __builtin_amdgcn_mfma_f32_16x16x32_bf16(pb, vh, oacc, 0, 0, 0);
    }
  }
  // C layout: col = d-within-subtile = lr, row = q = 4*lg + r
#pragma unroll
  for (int r = 0; r < 4; ++r) {
    int q = 4 * lg + r;
    int d = wv * 16 + lr;
    long ob = (long)(i0 + q) * 1024 + hq * HEADD + d;
    float v = oacc[r];
    short hb = f2bf(v);
    attHi[ob] = hb;
    attLo[ob] = f2bf(v - bf2f(hb));
  }
}

// ---------------- bf16 MFMA GEMM: C[M,N](f32) (+)= A[M,K] @ Bt[N,K]^T ----------------
template <int ATOMIC>
__global__ __launch_bounds__(256) void k_gemm_bf16(const short* __restrict__ A,
                                                   const short* __restrict__ Bt,
                                                   float* __restrict__ C,
                                                   int K, int ldA, int ldB, int ldC,
                                                   long sA, long sB, long sC) {
  __shared__ short As[128 * 64];
  __shared__ short Bs[128 * 64];
  const int e = blockIdx.z;
  A += (long)e * sA; Bt += (long)e * sB; C += (long)e * sC;
  const int r0 = blockIdx.x * 128, c0 = blockIdx.y * 128;
  const int tid = threadIdx.x;
  const int wid = tid >> 6, lane = tid & 63;
  const int wr = wid >> 1, wc = wid & 1;
  const int lr = lane & 15, lg = lane >> 4;
  f32x4 zero = {0.f, 0.f, 0.f, 0.f};
  f32x4 acc[4][4];
#pragma unroll
  for (int m = 0; m < 4; ++m)
#pragma unroll
    for (int n = 0; n < 4; ++n) acc[m][n] = zero;
  for (int k0 = 0; k0 < K; k0 += 64) {
#pragma unroll
    for (int it = 0; it < 4; ++it) {
      int flat = tid + it * 256;
      int row = flat >> 3, cb = (flat & 7) * 8;
      int d = swz(row, cb);
      *(uint4*)&As[d] = *(const uint4*)&A[(long)(r0 + row) * ldA + k0 + cb];
      *(uint4*)&Bs[d] = *(const uint4*)&Bt[(long)(c0 + row) * ldB + k0 + cb];
    }
    __syncthreads();
#pragma unroll
    for (int kk = 0; kk < 64; kk += 32) {
      bf16x8 af[4], bfr[4];
#pragma unroll
      for (int m = 0; m < 4; ++m) af[m] = *(const bf16x8*)&As[swz(wr * 64 + m * 16 + lr, kk + lg * 8)];
#pragma unroll
      for (int n = 0; n < 4; ++n) bfr[n] = *(const bf16x8*)&Bs[swz(wc * 64 + n * 16 + lr, kk + lg * 8)];
#pragma unroll
      for (int m = 0; m < 4; ++m)
#pragma unroll
        for (int n = 0; n < 4; ++n)
          acc[m][n] = __builtin_amdgcn_mfma_f32_16x16x32_bf16(af[m], bfr[n], acc[m][n], 0, 0, 0);
    }
    __syncthreads();
  }
#pragma unroll
  for (int m = 0; m < 4; ++m)
#pragma unroll
    for (int n = 0; n < 4; ++n) {
      int col = c0 + wc * 64 + n * 16 + lr;
#pragma unroll
      for (int r = 0; r < 4; ++r) {
        int row = r0 + wr * 64 + m * 16 + lg * 4 + r;
        float v = acc[m][n][r];
        if (ATOMIC) atomicAdd(&C[(long)row * ldC + col], v);
        else        C[(long)row * ldC + col] = v;
      }
    }
}

// ---------------- moe activation: a[e,t,f] = bf16( silu(g)*u * w_te ) ----------------
__global__ __launch_bounds__(256) void k_moe_act(const float* __restrict__ gu,
                                                 const float* __restrict__ wd,
                                                 short* __restrict__ aAll,
                                                 int e) {
  long i4 = (long)blockIdx.x * 256 + threadIdx.x;   // 2048*2048/4 = 1M float4
  int t  = (int)(i4 >> 9);
  int f4 = (int)(i4 & 511);
  float wte = wd[t * 4 + e];
  float4 g = ((const float4*)gu)[(long)t * 1024 + f4];
  float4 u = ((const float4*)gu)[(long)t * 1024 + 512 + f4];
  float4 s;
  s.x = wte * u.x * g.x / (1.f + expf(-g.x));
  s.y = wte * u.y * g.y / (1.f + expf(-g.y));
  s.z = wte * u.z * g.z / (1.f + expf(-g.z));
  s.w = wte * u.w * g.w / (1.f + expf(-g.w));
  ((uint2*)(aAll + ((long)e << 22)))[i4] =
      make_uint2(pk2(f2bf(s.x), f2bf(s.y)), pk2(f2bf(s.z), f2bf(s.w)));
}

extern "C" void kernel_launch(void* const* d_in, const int* in_sizes, int n_in,
                              void* d_out, int out_size, void* d_ws, size_t ws_size,
                              hipStream_t stream) {
  const float* x       = (const float*)d_in[0];
  const float* norm1_w = (const float*)d_in[1];
  const float* wq      = (const float*)d_in[2];
  const float* wk      = (const float*)d_in[3];
  const float* wv      = (const float*)d_in[4];
  const float* wo      = (const float*)d_in[5];
  const float* qn_w    = (const float*)d_in[6];
  const float* kn_w    = (const float*)d_in[7];
  const float* norm2_w = (const float*)d_in[8];
  const float* gate_w  = (const float*)d_in[9];
  const float* w_gate  = (const float*)d_in[10];
  const float* w_up    = (const float*)d_in[11];
  const float* w_down  = (const float*)d_in[12];
  float* out = (float*)d_out;
  char* ws = (char*)d_ws;
  const unsigned long MB = 1ul << 20;

  // workspace map (106 MB total; gu aliases [1,33); guT aliases dead h; Kb/Vt alias dT)
  float* ropeC = (float*)(ws + 0);               // 256 KB
  float* ropeS = (float*)(ws + 256 * 1024);      // 256 KB
  float* qkv   = (float*)(ws + 1 * MB);          // 16 MB  [1,17)
  short* xnHi  = (short*)(ws + 17 * MB);         // 4 MB
  short* xnLo  = (short*)(ws + 21 * MB);         // 4 MB
  short* attHi = (short*)(ws + 25 * MB);         // 4 MB
  short* attLo = (short*)(ws + 29 * MB);         // 4 MB
  float* gu    = (float*)(ws + 1 * MB);          // 32 MB, aliases qkv/xnS/attS (dead by MoE)
  short* qkvWh = (short*)(ws + 33 * MB);         // 4 MB
  short* qkvWl = (short*)(ws + 37 * MB);         // 4 MB
  short* woTh  = (short*)(ws + 41 * MB);         // 2 MB
  short* woTl  = (short*)(ws + 43 * MB);         // 2 MB
  float* h     = (float*)(ws + 45 * MB);         // 8 MB
  short* guT   = (short*)(ws + 45 * MB);         // 8 MB, aliases h (dead after memcpy)
  short* x2b   = (short*)(ws + 53 * MB);         // 4 MB
  float* wd    = (float*)(ws + 57 * MB);         // 32 KB
  short* dT    = (short*)(ws + 58 * MB);         // 16 MB [58,74)
  short* Kbh   = (short*)(ws + 58 * MB);         // 2 MB  (aliases dT: dead after attn)
  short* Kbl   = (short*)(ws + 60 * MB);         // 2 MB
  short* Vth   = (short*)(ws + 62 * MB);         // 2 MB
  short* Vtl   = (short*)(ws + 64 * MB);         // 2 MB
  short* aAll  = (short*)(ws + 74 * MB);         // 32 MB -> ends 106 MB

  k_rope_tables<<<256, 256, 0, stream>>>(ropeC, ropeS);
  k_rmsnorm<2><<<S_LEN, 256, 0, stream>>>(x, norm1_w, xnHi, xnLo, nullptr, nullptr);
  // transpose+split QKV weights into one Bt (2048 rows x 1024): q|k|v at rows 0|1024|1536
  k_tsplit<<<dim3(32, 32), 256, 0, stream>>>(wq, qkvWh, qkvWl, 1024, 1024);
  k_tsplit<<<dim3(16, 32), 256, 0, stream>>>(wk, qkvWh + 1024 * 1024, qkvWl + 1024 * 1024, 1024, 512);
  k_tsplit<<<dim3(16, 32), 256, 0, stream>>>(wv, qkvWh + 1536 * 1024, qkvWl + 1536 * 1024, 1024, 512);
  k_tsplit<<<dim3(32, 32), 256, 0, stream>>>(wo, woTh, woTl, 1024, 1024);
  // fused QKV projection (split-bf16 ~= fp32): qkv[t][0:1024|1024:1536|1536:2048]
  k_gemm_split<0><<<dim3(16, 16), 256, 0, stream>>>(xnHi, xnLo, qkvWh, qkvWl, nullptr, qkv,
                                                    1024, 1024, 1024, 2048);
  k_rope_rms<<<(S_LEN * 24) / 4, 256, 0, stream>>>(qkv, qn_w, kn_w, ropeC, ropeS);
  k_kv_split<<<dim3(S_LEN / 64, N_KVH), 256, 0, stream>>>(qkv, Kbh, Kbl, Vth, Vtl);
  k_attn2<<<dim3(S_LEN / QB, N_QH), 256, 0, stream>>>(qkv, Kbh, Kbl, Vth, Vtl, attHi, attLo);
  // h = x + att @ wo   (split-bf16 ~= fp32)
  k_gemm_split<1><<<dim3(16, 8), 256, 0, stream>>>(attHi, attLo, woTh, woTl, x, h,
                                                   1024, 1024, 1024, 1024);
  k_rmsnorm<3><<<S_LEN, 256, 0, stream>>>(h, norm2_w, x2b, nullptr, gate_w, wd);
  hipMemcpyAsync(out, h, (size_t)S_LEN * H_DIM * sizeof(float), hipMemcpyDeviceToDevice, stream);
  // bf16 down-proj weights (all experts, needed by batched GEMM2) — overwrites Kb/Vt (dead)
  for (int e = 0; e < N_EXP; ++e)
    k_transpose_cast<<<dim3(1024 / 32, 2048 / 32), 256, 0, stream>>>(
        w_down + (long)e * FF_DIM * H_DIM, dT + (long)e * H_DIM * FF_DIM, 2048, 1024);
  // per-expert: transpose gate/up -> guT (aliases dead h), GEMM1 (N=4096), act -> aAll[e]
  for (int e = 0; e < N_EXP; ++e) {
    k_transpose_cast<<<dim3(2048 / 32, 1024 / 32), 256, 0, stream>>>(
        w_gate + (long)e * H_DIM * FF_DIM, guT, 1024, 2048);
    k_transpose_cast<<<dim3(2048 / 32, 1024 / 32), 256, 0, stream>>>(
        w_up + (long)e * H_DIM * FF_DIM, guT + (long)FF_DIM * H_DIM, 1024, 2048);
    k_gemm_bf16<0><<<dim3(16, 32), 256, 0, stream>>>(x2b, guT, gu, 1024, 1024, 1024, 4096, 0, 0, 0);
    k_moe_act<<<4096, 256, 0, stream>>>(gu, wd, aAll, e);
  }
  // batched GEMM2 over experts: out += a[e] @ w_down[e]  (atomicAdd epilogue)
  k_gemm_bf16<1><<<dim3(16, 8, N_EXP), 256, 0, stream>>>(
      aAll, dT, out, 2048, 2048, 2048, 1024,
      (long)S_LEN * FF_DIM, (long)H_DIM * FF_DIM, 0);
}